// Round 3
// baseline (240.209 us; speedup 1.0000x reference)
//
#include <hip/hip_runtime.h>
#include <stdint.h>
#include <stddef.h>

#define IN_F   1024
#define OUT_F  1024
#define NROWS  16384
#define NTERMS 10

typedef __bf16 bf16x8 __attribute__((ext_vector_type(8)));
typedef float  f32x4  __attribute__((ext_vector_type(4)));
typedef unsigned short u16x8 __attribute__((ext_vector_type(8)));

union V8 { u16x8 u; bf16x8 b; };

__device__ __forceinline__ unsigned short f2bf(float f) {
    // round-to-nearest-even fp32 -> bf16 (inputs are finite normals)
    unsigned int u = __float_as_uint(f);
    unsigned int r = (u + 0x7FFFu + ((u >> 16) & 1u)) >> 16;
    return (unsigned short)r;
}

// ---------------------------------------------------------------- cast x -> bf16
__global__ void cast_x_kernel(const float* __restrict__ x, unsigned short* __restrict__ xb) {
    size_t i = ((size_t)blockIdx.x * 256 + threadIdx.x) * 8;
    float4 a = *(const float4*)(x + i);
    float4 b = *(const float4*)(x + i + 4);
    u16x8 o;
    o[0] = f2bf(a.x); o[1] = f2bf(a.y); o[2] = f2bf(a.z); o[3] = f2bf(a.w);
    o[4] = f2bf(b.x); o[5] = f2bf(b.y); o[6] = f2bf(b.z); o[7] = f2bf(b.w);
    *(u16x8*)(xb + i) = o;
}

// ------------------------------------------- base W -> bf16 ; mean spline W -> bf16
__global__ __launch_bounds__(256)
void prep_w_kernel(const float* __restrict__ bw, const float* __restrict__ sw,
                   unsigned short* __restrict__ wb, unsigned short* __restrict__ wm) {
    __shared__ float s[256 * NTERMS];
    const int tid = threadIdx.x;
    const size_t base = (size_t)blockIdx.x * 256;
    const float4* src = (const float4*)(sw + base * NTERMS);  // 640 float4 per block
#pragma unroll
    for (int it = 0; it < 3; ++it) {
        int j = tid + it * 256;
        if (j < (256 * NTERMS) / 4) ((float4*)s)[j] = src[j];
    }
    __syncthreads();
    float sum = 0.f;
#pragma unroll
    for (int t = 0; t < NTERMS; ++t) sum += s[tid * NTERMS + t];
    size_t i = base + tid;
    wm[i] = f2bf(sum * 0.1f);
    wb[i] = f2bf(bw[i]);
}

// ---------------------------------------------------------------- fused dual GEMM
// out[m][n] = silu( sum_k x[m][k]*Wb[n][k] ) + sum_k x[m][k]*Wm[n][k]
// Block: 256 threads (4 waves), tile BM=128 x BN=128 (per matrix), BK=32.
// Single-barrier double-buffered K-loop: stage tile k+1 right after the
// barrier, then ds_read/MFMA tile k — the compiler's vmcnt(0)-before-barrier
// drain lands a full iteration after issue, hiding the load latency.
__global__ __launch_bounds__(256, 2)
void kan_gemm(const unsigned short* __restrict__ xb,
              const unsigned short* __restrict__ wbq,
              const unsigned short* __restrict__ wmq,
              float* __restrict__ out) {
    __shared__ __align__(16) unsigned short As[2][128 * 32];
    __shared__ __align__(16) unsigned short Bs[2][2][128 * 32];

    const int tid  = threadIdx.x;
    const int lane = tid & 63;
    const int wave = tid >> 6;
    const int wm_  = wave >> 1;      // 0..1  (m half)
    const int wn_  = wave & 1;       // 0..1  (n half)
    const int rowl = lane & 15;
    const int quad = lane >> 4;

    const int m0 = blockIdx.x * 128;
    const int n0 = blockIdx.y * 128;

    f32x4 acc[2][4][4];
#pragma unroll
    for (int s = 0; s < 2; ++s)
#pragma unroll
        for (int mt = 0; mt < 4; ++mt)
#pragma unroll
            for (int nt = 0; nt < 4; ++nt)
                acc[s][mt][nt] = (f32x4){0.f, 0.f, 0.f, 0.f};

    // staging chunk decomposition: 512 chunks of 16B per 128x32 tile, 2/thread
    const int p0 = tid,       r0 = p0 >> 2, c0 = p0 & 3;
    const int p1 = tid + 256, r1 = p1 >> 2, c1 = p1 & 3;

#define STAGE(buf, k0)                                                                        \
    do {                                                                                      \
        const unsigned short* ga0 = xb + (size_t)(m0 + r0) * IN_F + (k0) + c0 * 8;            \
        __builtin_amdgcn_global_load_lds(                                                     \
            (const __attribute__((address_space(1))) unsigned int*)ga0,                       \
            (__attribute__((address_space(3))) unsigned int*)(As[buf] + p0 * 8), 16, 0, 0);   \
        const unsigned short* ga1 = xb + (size_t)(m0 + r1) * IN_F + (k0) + c1 * 8;            \
        __builtin_amdgcn_global_load_lds(                                                     \
            (const __attribute__((address_space(1))) unsigned int*)ga1,                       \
            (__attribute__((address_space(3))) unsigned int*)(As[buf] + p1 * 8), 16, 0, 0);   \
        const unsigned short* gb0 = wbq + (size_t)(n0 + r0) * IN_F + (k0) + c0 * 8;           \
        __builtin_amdgcn_global_load_lds(                                                     \
            (const __attribute__((address_space(1))) unsigned int*)gb0,                       \
            (__attribute__((address_space(3))) unsigned int*)(Bs[buf][0] + p0 * 8), 16, 0, 0);\
        const unsigned short* gb1 = wbq + (size_t)(n0 + r1) * IN_F + (k0) + c1 * 8;           \
        __builtin_amdgcn_global_load_lds(                                                     \
            (const __attribute__((address_space(1))) unsigned int*)gb1,                       \
            (__attribute__((address_space(3))) unsigned int*)(Bs[buf][0] + p1 * 8), 16, 0, 0);\
        const unsigned short* gm0 = wmq + (size_t)(n0 + r0) * IN_F + (k0) + c0 * 8;           \
        __builtin_amdgcn_global_load_lds(                                                     \
            (const __attribute__((address_space(1))) unsigned int*)gm0,                       \
            (__attribute__((address_space(3))) unsigned int*)(Bs[buf][1] + p0 * 8), 16, 0, 0);\
        const unsigned short* gm1 = wmq + (size_t)(n0 + r1) * IN_F + (k0) + c1 * 8;           \
        __builtin_amdgcn_global_load_lds(                                                     \
            (const __attribute__((address_space(1))) unsigned int*)gm1,                       \
            (__attribute__((address_space(3))) unsigned int*)(Bs[buf][1] + p1 * 8), 16, 0, 0);\
    } while (0)

    STAGE(0, 0);

    for (int it = 0; it < IN_F / 32; ++it) {
        __syncthreads();
        if (it + 1 < IN_F / 32) {
            STAGE((it + 1) & 1, (it + 1) * 32);
        }
        const int cur = it & 1;

        bf16x8 afrag[4], bfrag[2][4];
#pragma unroll
        for (int mt = 0; mt < 4; ++mt) {
            union V8 t;
            t.u = *(const u16x8*)(As[cur] + (wm_ * 64 + mt * 16 + rowl) * 32 + quad * 8);
            afrag[mt] = t.b;
        }
#pragma unroll
        for (int s = 0; s < 2; ++s)
#pragma unroll
            for (int nt = 0; nt < 4; ++nt) {
                union V8 t;
                t.u = *(const u16x8*)(Bs[cur][s] + (wn_ * 64 + nt * 16 + rowl) * 32 + quad * 8);
                bfrag[s][nt] = t.b;
            }
#pragma unroll
        for (int s = 0; s < 2; ++s)
#pragma unroll
            for (int mt = 0; mt < 4; ++mt)
#pragma unroll
                for (int nt = 0; nt < 4; ++nt)
                    acc[s][mt][nt] = __builtin_amdgcn_mfma_f32_16x16x32_bf16(
                        afrag[mt], bfrag[s][nt], acc[s][mt][nt], 0, 0, 0);
    }
#undef STAGE

    // epilogue: silu(base) + spline, fp32 store
    // C/D layout (16x16x32): col = lane&15, row = quad*4 + reg
#pragma unroll
    for (int mt = 0; mt < 4; ++mt)
#pragma unroll
        for (int nt = 0; nt < 4; ++nt)
#pragma unroll
            for (int r = 0; r < 4; ++r) {
                float vb = acc[0][mt][nt][r];
                float vm = acc[1][mt][nt][r];
                float o  = vb / (1.0f + __expf(-vb)) + vm;
                int row = m0 + wm_ * 64 + mt * 16 + quad * 4 + r;
                int col = n0 + wn_ * 64 + nt * 16 + rowl;
                out[(size_t)row * OUT_F + col] = o;
            }
}

extern "C" void kernel_launch(void* const* d_in, const int* in_sizes, int n_in,
                              void* d_out, int out_size, void* d_ws, size_t ws_size,
                              hipStream_t stream) {
    const float* x  = (const float*)d_in[0];   // [16384,1024]
    const float* bw = (const float*)d_in[1];   // [1024,1024]
    const float* sw = (const float*)d_in[2];   // [1024,1024,10]
    float* out = (float*)d_out;                // [16384,1024]

    unsigned short* xb  = (unsigned short*)d_ws;                 // 16384*1024
    unsigned short* wbq = xb + (size_t)NROWS * IN_F;             // 1024*1024
    unsigned short* wmq = wbq + (size_t)OUT_F * IN_F;            // 1024*1024

    cast_x_kernel<<<dim3((NROWS * IN_F) / (256 * 8)), dim3(256), 0, stream>>>(x, xb);
    prep_w_kernel<<<dim3((OUT_F * IN_F) / 256), dim3(256), 0, stream>>>(bw, sw, wbq, wmq);
    kan_gemm<<<dim3(NROWS / 128, OUT_F / 128), dim3(256), 0, stream>>>(xb, wbq, wmq, out);
}

// Round 4
// 208.006 us; speedup vs baseline: 1.1548x; 1.1548x over previous
//
#include <hip/hip_runtime.h>
#include <stdint.h>
#include <stddef.h>

#define IN_F   1024
#define OUT_F  1024
#define NROWS  16384
#define NTERMS 10

typedef __bf16 bf16x8 __attribute__((ext_vector_type(8)));
typedef float  f32x4  __attribute__((ext_vector_type(4)));
typedef unsigned short u16x8 __attribute__((ext_vector_type(8)));

union V8 { u16x8 u; bf16x8 b; };

__device__ __forceinline__ unsigned short f2bf(float f) {
    unsigned int u = __float_as_uint(f);
    unsigned int r = (u + 0x7FFFu + ((u >> 16) & 1u)) >> 16;
    return (unsigned short)r;
}

// ---------------------------------------------------------------- cast x -> bf16
__global__ void cast_x_kernel(const float* __restrict__ x, unsigned short* __restrict__ xb) {
    size_t i = ((size_t)blockIdx.x * 256 + threadIdx.x) * 8;
    float4 a = *(const float4*)(x + i);
    float4 b = *(const float4*)(x + i + 4);
    u16x8 o;
    o[0] = f2bf(a.x); o[1] = f2bf(a.y); o[2] = f2bf(a.z); o[3] = f2bf(a.w);
    o[4] = f2bf(b.x); o[5] = f2bf(b.y); o[6] = f2bf(b.z); o[7] = f2bf(b.w);
    *(u16x8*)(xb + i) = o;
}

// ------------------------------------------- base W -> bf16 ; mean spline W -> bf16
__global__ __launch_bounds__(256)
void prep_w_kernel(const float* __restrict__ bw, const float* __restrict__ sw,
                   unsigned short* __restrict__ wb, unsigned short* __restrict__ wm) {
    __shared__ float s[256 * NTERMS];
    const int tid = threadIdx.x;
    const size_t base = (size_t)blockIdx.x * 256;
    const float4* src = (const float4*)(sw + base * NTERMS);
#pragma unroll
    for (int it = 0; it < 3; ++it) {
        int j = tid + it * 256;
        if (j < (256 * NTERMS) / 4) ((float4*)s)[j] = src[j];
    }
    __syncthreads();
    float sum = 0.f;
#pragma unroll
    for (int t = 0; t < NTERMS; ++t) sum += s[tid * NTERMS + t];
    size_t i = base + tid;
    wm[i] = f2bf(sum * 0.1f);
    wb[i] = f2bf(bw[i]);
}

// ---------------------------------------------------------------- fused dual GEMM
// out[m][n] = silu( sum_k x[m][k]*Wb[n][k] ) + sum_k x[m][k]*Wm[n][k]
// 2-barrier m97 K-loop (proven best), BK=64, XOR bank swizzle.
// Tile layout: rows of 64 bf16 (128 B = 8 chunks of 16 B). Chunk c of row r is
// stored at LDS chunk slot (c ^ (r&7)); the staging lanes fetch the permuted
// global chunk so LDS dest stays wavebase+lane*16 (global_load_lds constraint).
__global__ __launch_bounds__(256, 2)
void kan_gemm(const unsigned short* __restrict__ xb,
              const unsigned short* __restrict__ wbq,
              const unsigned short* __restrict__ wmq,
              float* __restrict__ out) {
    __shared__ __align__(16) unsigned short As[128 * 64];
    __shared__ __align__(16) unsigned short Bs[2][128 * 64];

    const int tid  = threadIdx.x;
    const int lane = tid & 63;
    const int wave = tid >> 6;
    const int wm_  = wave >> 1;      // m half
    const int wn_  = wave & 1;       // n half
    const int rowl = lane & 15;
    const int quad = lane >> 4;

    const int m0 = blockIdx.x * 128;
    const int n0 = blockIdx.y * 128;

    f32x4 acc[2][4][4];
#pragma unroll
    for (int s = 0; s < 2; ++s)
#pragma unroll
        for (int mt = 0; mt < 4; ++mt)
#pragma unroll
            for (int nt = 0; nt < 4; ++nt)
                acc[s][mt][nt] = (f32x4){0.f, 0.f, 0.f, 0.f};

    // staging: 1024 chunks (16 B) per 128x64 tile, 4 per thread per tile
    int srow[4], sgc[4];   // row, swizzled global chunk (same for all 3 tiles)
#pragma unroll
    for (int j = 0; j < 4; ++j) {
        int q = tid + j * 256;
        int r = q >> 3, cd = q & 7;
        srow[j] = r;
        sgc[j] = cd ^ (r & 7);
    }

    for (int k0 = 0; k0 < IN_F; k0 += 64) {
        __syncthreads();
#pragma unroll
        for (int j = 0; j < 4; ++j) {
            int q = tid + j * 256;
            const unsigned short* ga = xb + (size_t)(m0 + srow[j]) * IN_F + k0 + sgc[j] * 8;
            __builtin_amdgcn_global_load_lds(
                (const __attribute__((address_space(1))) unsigned int*)ga,
                (__attribute__((address_space(3))) unsigned int*)(As + q * 8), 16, 0, 0);
            const unsigned short* gb = wbq + (size_t)(n0 + srow[j]) * IN_F + k0 + sgc[j] * 8;
            __builtin_amdgcn_global_load_lds(
                (const __attribute__((address_space(1))) unsigned int*)gb,
                (__attribute__((address_space(3))) unsigned int*)(Bs[0] + q * 8), 16, 0, 0);
            const unsigned short* gm = wmq + (size_t)(n0 + srow[j]) * IN_F + k0 + sgc[j] * 8;
            __builtin_amdgcn_global_load_lds(
                (const __attribute__((address_space(1))) unsigned int*)gm,
                (__attribute__((address_space(3))) unsigned int*)(Bs[1] + q * 8), 16, 0, 0);
        }
        __syncthreads();

#pragma unroll
        for (int ksub = 0; ksub < 2; ++ksub) {
            bf16x8 afrag[4], bfrag[2][4];
#pragma unroll
            for (int mt = 0; mt < 4; ++mt) {
                int r = wm_ * 64 + mt * 16 + rowl;
                int c = (ksub * 4 + quad) ^ (r & 7);
                union V8 t;
                t.u = *(const u16x8*)(As + r * 64 + c * 8);
                afrag[mt] = t.b;
            }
#pragma unroll
            for (int s = 0; s < 2; ++s)
#pragma unroll
                for (int nt = 0; nt < 4; ++nt) {
                    int r = wn_ * 64 + nt * 16 + rowl;
                    int c = (ksub * 4 + quad) ^ (r & 7);
                    union V8 t;
                    t.u = *(const u16x8*)(Bs[s] + r * 64 + c * 8);
                    bfrag[s][nt] = t.b;
                }
#pragma unroll
            for (int s = 0; s < 2; ++s)
#pragma unroll
                for (int mt = 0; mt < 4; ++mt)
#pragma unroll
                    for (int nt = 0; nt < 4; ++nt)
                        acc[s][mt][nt] = __builtin_amdgcn_mfma_f32_16x16x32_bf16(
                            afrag[mt], bfrag[s][nt], acc[s][mt][nt], 0, 0, 0);
        }
    }

    // epilogue: silu(base) + spline, fp32 store
    // C/D layout (16x16x32): col = lane&15, row = quad*4 + reg
#pragma unroll
    for (int mt = 0; mt < 4; ++mt)
#pragma unroll
        for (int nt = 0; nt < 4; ++nt)
#pragma unroll
            for (int r = 0; r < 4; ++r) {
                float vb = acc[0][mt][nt][r];
                float vm = acc[1][mt][nt][r];
                float o  = vb / (1.0f + __expf(-vb)) + vm;
                int row = m0 + wm_ * 64 + mt * 16 + quad * 4 + r;
                int col = n0 + wn_ * 64 + nt * 16 + rowl;
                out[(size_t)row * OUT_F + col] = o;
            }
}

extern "C" void kernel_launch(void* const* d_in, const int* in_sizes, int n_in,
                              void* d_out, int out_size, void* d_ws, size_t ws_size,
                              hipStream_t stream) {
    const float* x  = (const float*)d_in[0];   // [16384,1024]
    const float* bw = (const float*)d_in[1];   // [1024,1024]
    const float* sw = (const float*)d_in[2];   // [1024,1024,10]
    float* out = (float*)d_out;                // [16384,1024]

    unsigned short* xb  = (unsigned short*)d_ws;
    unsigned short* wbq = xb + (size_t)NROWS * IN_F;
    unsigned short* wmq = wbq + (size_t)OUT_F * IN_F;

    cast_x_kernel<<<dim3((NROWS * IN_F) / (256 * 8)), dim3(256), 0, stream>>>(x, xb);
    prep_w_kernel<<<dim3((OUT_F * IN_F) / 256), dim3(256), 0, stream>>>(bw, sw, wbq, wmq);
    kan_gemm<<<dim3(NROWS / 128, OUT_F / 128), dim3(256), 0, stream>>>(xb, wbq, wmq, out);
}